// Round 5
// baseline (331.954 us; speedup 1.0000x reference)
//
#include <hip/hip_runtime.h>
#include <hip/hip_bf16.h>

// GAT layer, fused. fp32 in/out, bf16 MFMA internally.
// B=65536, N=2, F=256, H=4, D=256, mean over heads.
// v5b: v4 schedule, HALF tile (TB=16, 32 rows) -> LDS 25600 B -> 6 blocks/CU
// by LDS, ~5 waves/SIMD by VGPR (launch_bounds 256,5; acc[2][4]=32 AGPR).
// 20-24 waves/CU (was 9.6): block barrier drains hidden by 5-6 independent
// blocks per SIMD. Same pipelined 1-barrier-per-chunk phase 3.
// (v5b = v5 with ptf initialized on all waves — closes a formal-UB hole;
//  resubmit after container-level failure with no kernel diagnostic.)

typedef __attribute__((ext_vector_type(8))) short short8;
typedef __attribute__((ext_vector_type(4))) float floatx4;

__device__ __forceinline__ float bf2f(short u) {
    union { unsigned int i; float f; } v;
    v.i = ((unsigned int)(unsigned short)u) << 16;
    return v.f;
}
// pack two fp32 -> one u32 of 2 bf16 (RNE), low = first
__device__ __forceinline__ unsigned int pk2(float lo, float hi) {
    __hip_bfloat162 t = __float22bfloat162_rn(make_float2(lo, hi));
    union { __hip_bfloat162 h; unsigned int u; } cv; cv.h = t;
    return cv.u;
}

// ---- fused prep ----
// blocks [0,1024): Wt2[((hh*8+j)*256 + d)*32 + kl] = bf16(W[(j*32+kl)*1024 + hh*256 + d])
//   (fragment-ordered: a B-frag wave load is 1KB contiguous)
// blocks [1024,1536): one wave per dot-product PT[n][k], n = half*4+h
__global__ void gat_prep(const float* __restrict__ W, const float* __restrict__ a,
                         __hip_bfloat16* __restrict__ PT,
                         __hip_bfloat16* __restrict__ Wt2) {
    int b = blockIdx.x;
    if (b < 1024) {
        int idx = b * 256 + threadIdx.x;          // 262144, coalesced W reads
        int d = idx & 255, hh = (idx >> 8) & 3, k = idx >> 10;
        int j = k >> 5, kl = k & 31;
        Wt2[(((hh * 8 + j) * 256 + d) << 5) + kl] =
            __float2bfloat16(W[k * 1024 + hh * 256 + d]);
    } else {
        int wid = (b - 1024) * 4 + (threadIdx.x >> 6);   // 2048 waves
        int lane = threadIdx.x & 63;
        int k = wid & 255, h = (wid >> 8) & 3, half = wid >> 10;
        float4 wv = *(const float4*)(W + k * 1024 + h * 256 + lane * 4);
        float4 av = *(const float4*)(a + h * 512 + half * 256 + lane * 4);
        float s = wv.x * av.x + wv.y * av.y + wv.z * av.z + wv.w * av.w;
        #pragma unroll
        for (int off = 32; off; off >>= 1) s += __shfl_down(s, off);
        if (lane == 0) PT[(half * 4 + h) * 256 + k] = __float2bfloat16(s);
        if (lane == 1) PT[2048 + wid] = __float2bfloat16(0.f);  // zero rows 8..15
    }
}

#define TB 16          // batches per block -> 32 rows
#define ROWS 32

__global__ __launch_bounds__(256, 5)
void gat_main(const float* __restrict__ hin,
              const int* __restrict__ adj,
              const __hip_bfloat16* __restrict__ PT,
              const __hip_bfloat16* __restrict__ Wt2,
              float* __restrict__ out) {
    __shared__ __align__(16) short sH[ROWS * 256];   // 16384 B, XOR-swizzled
    __shared__ __align__(16) short sZd[2][ROWS * 64];// 2 x 4096 B, XOR-swizzled
    __shared__ __align__(16) float2 sC[TB * 4 * 2];  //  1024 B
    // sS (32x16 f32 = 2048 B) unioned into sZd[1] (dead until loop iter 0)
    float (*sS)[16] = (float (*)[16])(&sZd[1][0]);

    const int tid = threadIdx.x;
    const int lane = tid & 63;
    const int wave = tid >> 6;
    const int m = lane & 15;     // MFMA row/col index
    const int q = lane >> 4;     // MFMA quad
    const long batch0 = (long)blockIdx.x * TB;
    char* sHb = (char*)sH;
    char* sZb = (char*)sZd;

    // prefetch phase-1 B-frags (PT, L2-hot; used by waves 0-1) and adj
    short8 ptf[8];
    {
        const short* ptg = (const short*)PT;
        int mm = (wave < 2) ? m : 0;     // waves 2-3: harmless dup load, no UB
        #pragma unroll
        for (int ks = 0; ks < 8; ++ks)
            ptf[ks] = *(const short8*)(ptg + mm * 256 + ks * 32 + q * 8);
    }
    int4 av = ((const int4*)adj)[batch0 + ((tid >> 3) & 15)];

    // stage H tile: 32 rows x 256 fp32 -> bf16, XOR-swizzled LDS
    // swizzle: byte_off_in_row ^= (row&7)<<4  (16B-granular, bijective)
    {
        const float4* gh = (const float4*)(hin + batch0 * 512);
        #pragma unroll
        for (int it = 0; it < 8; ++it) {
            int idx = tid + it * 256;       // 2048 float4 per block
            int r = idx >> 6, c4 = idx & 63;
            float4 v = gh[idx];
            uint2 bv;
            bv.x = pk2(v.x, v.y);
            bv.y = pk2(v.z, v.w);
            *(uint2*)(sHb + r * 512 + ((c4 * 8) ^ ((r & 7) << 4))) = bv;
        }
    }
    __syncthreads();

    // phase 1: S = H(32x256) @ P^T(256x16), waves 0-1 (one M-tile each)
    if (wave < 2) {
        int row = wave * 16 + m;
        floatx4 a0 = {0.f, 0.f, 0.f, 0.f};
        #pragma unroll
        for (int ks = 0; ks < 8; ++ks) {
            short8 f0 = *(const short8*)(sHb + row * 512 +
                          ((ks * 64 + q * 16) ^ ((row & 7) << 4)));
            a0 = __builtin_amdgcn_mfma_f32_16x16x32_bf16(f0, ptf[ks], a0, 0, 0, 0);
        }
        #pragma unroll
        for (int r = 0; r < 4; ++r)       // C-layout: col=lane&15, row=q*4+r
            sS[wave * 16 + q * 4 + r][m] = a0[r];
    }
    __syncthreads();

    // phase 2: masked 2-way softmax -> c = attn/4. thread = (batch, head, row)
    if (tid < 128) {
        int lb = tid >> 3, hh = (tid >> 1) & 3, i = tid & 1;
        int m0 = i ? av.z : av.x, m1 = i ? av.w : av.y;
        float s  = sS[lb * 2 + i][hh];
        float t0 = sS[lb * 2][4 + hh], t1 = sS[lb * 2 + 1][4 + hh];
        float e0 = s + t0; e0 = e0 >= 0.f ? e0 : 0.2f * e0;
        float e1 = s + t1; e1 = e1 >= 0.f ? e1 : 0.2f * e1;
        e0 = fminf(fmaxf(e0, -80.f), 80.f);
        e1 = fminf(fmaxf(e1, -80.f), 80.f);
        bool k0 = m0 > 0, k1 = m1 > 0;    // diag forced 1 by setup
        float f0 = k0 ? e0 : -1e30f, f1 = k1 ? e1 : -1e30f;
        float mx = fmaxf(f0, f1);
        float p0 = k0 ? __expf(e0 - mx) : 0.f;
        float p1 = k1 ? __expf(e1 - mx) : 0.f;
        float den = p0 + p1;
        float inv = den > 1e-30f ? 0.25f / den : 0.f;
        sC[(lb * 4 + hh) * 2 + i] = make_float2(p0 * inv, p1 * inv);
    }
    __syncthreads();

    // phase 3: out(32x256) = sum over 16 chunks of Z_ch(32x64) @ W_ch(64x256).
    // chunk ch: head hh=ch>>2, 64-K slice kc=ch&3. Double-buffered sZ, ONE
    // barrier per chunk: interval = {B-loads(ch) ; Zbuild(ch+1) ; MFMA(ch)}.
    const int zg = tid & 7, zr = tid >> 3;   // Zbuild: 1 int4 per thread

    #define ZBUILD(ch, buf)                                                     \
    {                                                                           \
        int hh_ = (ch) >> 2, kc_ = (ch) & 3;                                    \
        float2 c = sC[((zr >> 1) * 4 + hh_) * 2 + (zr & 1)];                    \
        int hr = zr & ~1;                                                       \
        int co = kc_ * 128 + zg * 16;                                           \
        short8 v0 = *(const short8*)(sHb + hr * 512 + (co ^ ((hr & 7) << 4)));  \
        short8 v1 = *(const short8*)(sHb + (hr + 1) * 512 + (co ^ (((hr + 1) & 7) << 4))); \
        int4 zv; int* zp = (int*)&zv;                                           \
        _Pragma("unroll")                                                       \
        for (int jj = 0; jj < 4; ++jj) {                                        \
            float z0 = c.x * bf2f(v0[jj * 2])     + c.y * bf2f(v1[jj * 2]);     \
            float z1 = c.x * bf2f(v0[jj * 2 + 1]) + c.y * bf2f(v1[jj * 2 + 1]); \
            zp[jj] = (int)pk2(z0, z1);                                          \
        }                                                                       \
        *(int4*)(sZb + (buf) * 4096 + zr * 128 + ((zg * 16) ^ ((zr & 7) << 4))) = zv; \
    }

    floatx4 acc[2][4];
    #pragma unroll
    for (int i = 0; i < 2; ++i)
        #pragma unroll
        for (int j = 0; j < 4; ++j)
            acc[i][j] = (floatx4){0.f, 0.f, 0.f, 0.f};

    ZBUILD(0, 0);
    __syncthreads();

    int cur = 0;
    #pragma unroll 1
    for (int ch = 0; ch < 16; ++ch) {
        // B-frag loads for this chunk (L2-resident Wt2); latency covered by Zbuild
        short8 bfr[2][4];
        {
            int hh = ch >> 2, kc = ch & 3;
            #pragma unroll
            for (int ks = 0; ks < 2; ++ks) {
                const short* wb = (const short*)Wt2 +
                    (((hh * 8 + kc * 2 + ks) * 256 + wave * 64 + m) << 5) + q * 8;
                #pragma unroll
                for (int nt = 0; nt < 4; ++nt)
                    bfr[ks][nt] = *(const short8*)(wb + (nt << 9));
            }
        }
        // build next chunk into the other buffer (overlaps loads + MFMA)
        if (ch < 15) ZBUILD(ch + 1, cur ^ 1);
        // MFMA current chunk
        #pragma unroll
        for (int ks = 0; ks < 2; ++ks)
            #pragma unroll
            for (int mt = 0; mt < 2; ++mt) {
                int row = mt * 16 + m;
                short8 af = *(const short8*)(sZb + cur * 4096 + row * 128 +
                              ((ks * 64 + q * 16) ^ ((row & 7) << 4)));
                #pragma unroll
                for (int nt = 0; nt < 4; ++nt)
                    acc[mt][nt] = __builtin_amdgcn_mfma_f32_16x16x32_bf16(
                        af, bfr[ks][nt], acc[mt][nt], 0, 0, 0);
            }
        __syncthreads();
        cur ^= 1;
    }

    // epilogue: direct fp32 stores, 16 lanes = 64B contiguous per instruction
    {
        float* og = out + batch0 * 512;
        #pragma unroll
        for (int mt = 0; mt < 2; ++mt)
            #pragma unroll
            for (int nt = 0; nt < 4; ++nt) {
                int col = wave * 64 + nt * 16 + m;
                #pragma unroll
                for (int r = 0; r < 4; ++r)
                    og[(mt * 16 + q * 4 + r) * 256 + col] = acc[mt][nt][r];
            }
    }
    #undef ZBUILD
}

extern "C" void kernel_launch(void* const* d_in, const int* in_sizes, int n_in,
                              void* d_out, int out_size, void* d_ws, size_t ws_size,
                              hipStream_t stream) {
    const float* hin = (const float*)d_in[0];
    const int* adj   = (const int*)d_in[1];
    const float* W   = (const float*)d_in[2];
    const float* a   = (const float*)d_in[3];
    float* out       = (float*)d_out;

    __hip_bfloat16* PT  = (__hip_bfloat16*)d_ws;  // 16*256 bf16 = 8 KB
    __hip_bfloat16* Wt2 = PT + 16 * 256;          // 32*256*32 bf16 = 512 KB

    // ws guard: leaves out poisoned -> diagnostic, not corruption
    if (ws_size < (16 * 256 + 256 * 1024) * sizeof(__hip_bfloat16)) return;

    int B = in_sizes[0] / 512;                    // 65536
    gat_prep<<<1536, 256, 0, stream>>>(W, a, PT, Wt2);
    gat_main<<<B / TB, 256, 0, stream>>>(hin, adj, PT, Wt2, out);
}